// Round 1
// baseline (54.083 us; speedup 1.0000x reference)
//
#include <hip/hip_runtime.h>
#include <cstdint>

#define HD __device__ __forceinline__

constexpr int B = 4, N = 8192, H = 128, W = 128, K = 8;
constexpr float BIGF = 1e10f;

// ---- tiling for the binned path ----
constexpr int TP = 8;                      // tile edge in pixels
constexpr int TILES_X = W / TP;            // 16
constexpr int TILES_Y = H / TP;            // 16
constexpr int TILES_PER_IMG = TILES_X * TILES_Y;  // 256
constexpr int NTILES = B * TILES_PER_IMG;  // 1024
constexpr int CAP = 256;                   // expected max ~80 per tile

HD bool keyless(float z1, int i1, float z2, int i2) {
    return (z1 < z2) || ((z1 == z2) && (i1 < i2));
}

// branchless unrolled insert into ascending (z,idx)-sorted top-K registers.
// Caller guarantees keyless(nz,ni, zk[K-1],ik[K-1]).
HD void insert_topk(float nz, int ni, float nd,
                    float (&zk)[K], int (&ik)[K], float (&dk)[K]) {
    bool lt[K];
#pragma unroll
    for (int j = 0; j < K; ++j) lt[j] = keyless(nz, ni, zk[j], ik[j]);
#pragma unroll
    for (int j = K - 1; j >= 1; --j) {
        if (lt[j]) {
            if (lt[j - 1]) { zk[j] = zk[j - 1]; ik[j] = ik[j - 1]; dk[j] = dk[j - 1]; }
            else           { zk[j] = nz;        ik[j] = ni;        dk[j] = nd; }
        }
    }
    if (lt[0]) { zk[0] = nz; ik[0] = ni; dk[0] = nd; }
}

HD void transform_point(const float* __restrict__ w2v, const float* __restrict__ p2n,
                        float x, float y, float z,
                        float& xn, float& yn, float& zn) {
    float ph0 = x, ph1 = y, ph2 = z, ph3 = 1.0f;
    float pv[4];
#pragma unroll
    for (int j = 0; j < 4; ++j)
        pv[j] = ph0 * w2v[0 * 4 + j] + ph1 * w2v[1 * 4 + j] +
                ph2 * w2v[2 * 4 + j] + ph3 * w2v[3 * 4 + j];
    float viewz = pv[2];
    float q[4];
#pragma unroll
    for (int j = 0; j < 4; ++j)
        q[j] = pv[0] * p2n[0 * 4 + j] + pv[1] * p2n[1 * 4 + j] +
               pv[2] * p2n[2 * 4 + j] + pv[3] * p2n[3 * 4 + j];
    float wq = q[3];
    float sgn = (wq >= 0.0f) ? 1.0f : -1.0f;
    float denom = sgn * fmaxf(fabsf(wq), 1e-6f);
    xn = q[0] / denom;
    yn = q[1] / denom;
    zn = viewz;
}

HD void process_candidate(float4 p, float px, float py, float r2,
                          float (&zk)[K], int (&ik)[K], float (&dk)[K]) {
    float dx = p.x - px, dy = p.y - py;
    float d2 = __fadd_rn(__fmul_rn(dx, dx), __fmul_rn(dy, dy));
    int pi = __float_as_int(p.w);
    if ((d2 <= r2) && (p.z > 0.0f) && keyless(p.z, pi, zk[K - 1], ik[K - 1]))
        insert_topk(p.z, pi, d2, zk, ik, dk);
}

HD void write_out(float* __restrict__ out, int b, int h, int w,
                  const float (&zk)[K], const int (&ik)[K], const float (&dk)[K]) {
    const size_t S = (size_t)B * H * W * K;
    size_t pix = (((size_t)b * H + h) * W + w) * K;
#pragma unroll
    for (int j = 0; j < K; ++j) {
        bool valid = zk[j] < 0.5f * BIGF;
        float fi = valid ? (float)ik[j] : -1.0f;
        float fz = valid ? zk[j] : -1.0f;
        float fd = valid ? dk[j] : -1.0f;
        out[pix + j]         = fi;
        out[S + pix + j]     = fz;
        out[2 * S + pix + j] = fi;
        out[3 * S + pix + j] = fd;
    }
}

// ---------------- phase 1: transform + bin ----------------
__global__ __launch_bounds__(256) void transform_bin_kernel(
    const float* __restrict__ points, const float* __restrict__ w2v,
    const float* __restrict__ p2n, int* __restrict__ cnt,
    float4* __restrict__ entries) {
    int gid = blockIdx.x * 256 + threadIdx.x;
    if (gid >= B * N) return;
    int b = gid >> 13;           // N = 8192
    int n = gid & (N - 1);
    float x = points[(size_t)gid * 3 + 0];
    float y = points[(size_t)gid * 3 + 1];
    float z = points[(size_t)gid * 3 + 2];
    float xn, yn, zn;
    transform_point(w2v, p2n, x, y, z, xn, yn, zn);
    if (!(zn > 0.0f)) return;    // can never be "inside"

    const float rbin = 0.0201f;  // conservative: RADIUS + slack
    int wmin = (int)ceilf(((1.0f - xn) - rbin) * 64.0f - 0.5f);
    int wmax = (int)floorf(((1.0f - xn) + rbin) * 64.0f - 0.5f);
    int hmin = (int)ceilf(((1.0f - yn) - rbin) * 64.0f - 0.5f);
    int hmax = (int)floorf(((1.0f - yn) + rbin) * 64.0f - 0.5f);
    wmin = max(wmin, 0); wmax = min(wmax, W - 1);
    hmin = max(hmin, 0); hmax = min(hmax, H - 1);
    if (wmin > wmax || hmin > hmax) return;

    int txmin = wmin >> 3, txmax = wmax >> 3;
    int tymin = hmin >> 3, tymax = hmax >> 3;
    float4 e; e.x = xn; e.y = yn; e.z = zn; e.w = __int_as_float(n);
    for (int ty = tymin; ty <= tymax; ++ty)
        for (int tx = txmin; tx <= txmax; ++tx) {
            int t = b * TILES_PER_IMG + ty * TILES_X + tx;
            int pos = atomicAdd(&cnt[t], 1);
            if (pos < CAP) entries[(size_t)t * CAP + pos] = e;
        }
}

// ---------------- phase 2: per-tile rasterize ----------------
__global__ __launch_bounds__(64) void raster_kernel(
    const int* __restrict__ cnt, const float4* __restrict__ entries,
    float* __restrict__ out) {
    int t = blockIdx.x;              // 0..NTILES-1
    int b = t >> 8;                  // 256 tiles per image
    int ti = t & 255;
    int ty = ti >> 4, tx = ti & 15;
    int lane = threadIdx.x;          // 0..63
    int h = ty * TP + (lane >> 3);
    int w = tx * TP + (lane & 7);
    float px = 1.0f - (2.0f * (float)w + 1.0f) / 128.0f;
    float py = 1.0f - (2.0f * (float)h + 1.0f) / 128.0f;
    const float r2 = (float)(0.02 * 0.02);

    __shared__ float4 sh[64];

    float zk[K]; int ik[K]; float dk[K];
#pragma unroll
    for (int j = 0; j < K; ++j) { zk[j] = BIGF; ik[j] = 0x7fffffff; dk[j] = 0.0f; }

    int count = cnt[t];
    if (count > CAP) count = CAP;
    const float4* base = entries + (size_t)t * CAP;

    for (int c = 0; c < count; c += 64) {
        __syncthreads();
        if (c + lane < count) sh[lane] = base[c + lane];
        __syncthreads();
        int m = min(64, count - c);
        for (int e = 0; e < m; ++e)
            process_candidate(sh[e], px, py, r2, zk, ik, dk);
    }
    write_out(out, b, h, w, zk, ik, dk);
}

// ---------------- fallback: brute force (no workspace needed) ----------------
__global__ __launch_bounds__(256) void brute_kernel(
    const float* __restrict__ points, const float* __restrict__ w2v,
    const float* __restrict__ p2n, float* __restrict__ out) {
    int gid = blockIdx.x * 256 + threadIdx.x;   // 0..B*H*W-1
    int b = gid >> 14;                           // H*W = 16384
    int rem = gid & 16383;
    int h = rem >> 7, w = rem & 127;
    float px = 1.0f - (2.0f * (float)w + 1.0f) / 128.0f;
    float py = 1.0f - (2.0f * (float)h + 1.0f) / 128.0f;
    const float r2 = (float)(0.02 * 0.02);

    __shared__ float4 sh[256];

    float zk[K]; int ik[K]; float dk[K];
#pragma unroll
    for (int j = 0; j < K; ++j) { zk[j] = BIGF; ik[j] = 0x7fffffff; dk[j] = 0.0f; }

    for (int c = 0; c < N; c += 256) {
        __syncthreads();
        int n = c + threadIdx.x;
        float x = points[((size_t)b * N + n) * 3 + 0];
        float y = points[((size_t)b * N + n) * 3 + 1];
        float z = points[((size_t)b * N + n) * 3 + 2];
        float xn, yn, zn;
        transform_point(w2v, p2n, x, y, z, xn, yn, zn);
        sh[threadIdx.x] = make_float4(xn, yn, zn, __int_as_float(n));
        __syncthreads();
        for (int e = 0; e < 256; ++e)
            process_candidate(sh[e], px, py, r2, zk, ik, dk);
    }
    write_out(out, b, h, w, zk, ik, dk);
}

extern "C" void kernel_launch(void* const* d_in, const int* in_sizes, int n_in,
                              void* d_out, int out_size, void* d_ws, size_t ws_size,
                              hipStream_t stream) {
    const float* points = (const float*)d_in[0];
    const float* w2v    = (const float*)d_in[1];
    const float* p2n    = (const float*)d_in[2];
    float* out = (float*)d_out;

    const size_t cnt_bytes = (size_t)NTILES * sizeof(int);       // 4 KB
    const size_t ent_off   = 4096;
    const size_t need      = ent_off + (size_t)NTILES * CAP * sizeof(float4); // ~4.2 MB

    if (ws_size >= need) {
        int* cnt = (int*)d_ws;
        float4* entries = (float4*)((char*)d_ws + ent_off);
        hipMemsetAsync(cnt, 0, cnt_bytes, stream);
        transform_bin_kernel<<<(B * N + 255) / 256, 256, 0, stream>>>(points, w2v, p2n, cnt, entries);
        raster_kernel<<<NTILES, 64, 0, stream>>>(cnt, entries, out);
    } else {
        brute_kernel<<<(B * H * W) / 256, 256, 0, stream>>>(points, w2v, p2n, out);
    }
}

// Round 2
// 53.639 us; speedup vs baseline: 1.0083x; 1.0083x over previous
//
#include <hip/hip_runtime.h>
#include <cstdint>

#define HD __device__ __forceinline__

constexpr int B = 4, N = 8192, H = 128, W = 128, K = 8;
constexpr float BIGF = 1e10f;

// ---- tiling for the binned path ----
constexpr int TP = 8;                      // tile edge in pixels
constexpr int TILES_X = W / TP;            // 16
constexpr int TILES_Y = H / TP;            // 16
constexpr int TILES_PER_IMG = TILES_X * TILES_Y;  // 256
constexpr int NTILES = B * TILES_PER_IMG;  // 1024
constexpr int CAP = 256;                   // expected max ~100 per tile

HD bool keyless(float z1, int i1, float z2, int i2) {
    return (z1 < z2) || ((z1 == z2) && (i1 < i2));
}

// branchless unrolled insert into ascending (z,idx)-sorted top-K registers.
// Caller guarantees keyless(nz,ni, zk[K-1],ik[K-1]).
HD void insert_topk(float nz, int ni, float nd,
                    float (&zk)[K], int (&ik)[K], float (&dk)[K]) {
    bool lt[K];
#pragma unroll
    for (int j = 0; j < K; ++j) lt[j] = keyless(nz, ni, zk[j], ik[j]);
#pragma unroll
    for (int j = K - 1; j >= 1; --j) {
        if (lt[j]) {
            if (lt[j - 1]) { zk[j] = zk[j - 1]; ik[j] = ik[j - 1]; dk[j] = dk[j - 1]; }
            else           { zk[j] = nz;        ik[j] = ni;        dk[j] = nd; }
        }
    }
    if (lt[0]) { zk[0] = nz; ik[0] = ni; dk[0] = nd; }
}

HD void transform_point(const float* __restrict__ w2v, const float* __restrict__ p2n,
                        float x, float y, float z,
                        float& xn, float& yn, float& zn) {
    float pv[4];
#pragma unroll
    for (int j = 0; j < 4; ++j)
        pv[j] = x * w2v[0 * 4 + j] + y * w2v[1 * 4 + j] +
                z * w2v[2 * 4 + j] + 1.0f * w2v[3 * 4 + j];
    float viewz = pv[2];
    float q[4];
#pragma unroll
    for (int j = 0; j < 4; ++j)
        q[j] = pv[0] * p2n[0 * 4 + j] + pv[1] * p2n[1 * 4 + j] +
               pv[2] * p2n[2 * 4 + j] + pv[3] * p2n[3 * 4 + j];
    float wq = q[3];
    float sgn = (wq >= 0.0f) ? 1.0f : -1.0f;
    float denom = sgn * fmaxf(fabsf(wq), 1e-6f);
    xn = q[0] / denom;
    yn = q[1] / denom;
    zn = viewz;
}

HD void process_candidate(float4 p, float px, float py, float r2,
                          float (&zk)[K], int (&ik)[K], float (&dk)[K]) {
    float dx = p.x - px, dy = p.y - py;
    float d2 = __fadd_rn(__fmul_rn(dx, dx), __fmul_rn(dy, dy));
    int pi = __float_as_int(p.w);
    if ((d2 <= r2) && (p.z > 0.0f) && keyless(p.z, pi, zk[K - 1], ik[K - 1]))
        insert_topk(p.z, pi, d2, zk, ik, dk);
}

HD void write_out(float* __restrict__ out, int b, int h, int w,
                  const float (&zk)[K], const int (&ik)[K], const float (&dk)[K]) {
    const size_t S = (size_t)B * H * W * K;
    size_t pix = (((size_t)b * H + h) * W + w) * K;
    float fi[K], fz[K], fd[K];
#pragma unroll
    for (int j = 0; j < K; ++j) {
        bool valid = zk[j] < 0.5f * BIGF;
        fi[j] = valid ? (float)ik[j] : -1.0f;
        fz[j] = valid ? zk[j] : -1.0f;
        fd[j] = valid ? dk[j] : -1.0f;
    }
    // pix is a multiple of 8 -> 32B-aligned; write 2x float4 per plane.
    float4* o0 = reinterpret_cast<float4*>(out + pix);
    float4* o1 = reinterpret_cast<float4*>(out + S + pix);
    float4* o2 = reinterpret_cast<float4*>(out + 2 * S + pix);
    float4* o3 = reinterpret_cast<float4*>(out + 3 * S + pix);
    o0[0] = make_float4(fi[0], fi[1], fi[2], fi[3]);
    o0[1] = make_float4(fi[4], fi[5], fi[6], fi[7]);
    o1[0] = make_float4(fz[0], fz[1], fz[2], fz[3]);
    o1[1] = make_float4(fz[4], fz[5], fz[6], fz[7]);
    o2[0] = make_float4(fi[0], fi[1], fi[2], fi[3]);
    o2[1] = make_float4(fi[4], fi[5], fi[6], fi[7]);
    o3[0] = make_float4(fd[0], fd[1], fd[2], fd[3]);
    o3[1] = make_float4(fd[4], fd[5], fd[6], fd[7]);
}

// ---------------- phase 0: zero tile counters (replaces hipMemsetAsync) ----
__global__ __launch_bounds__(256) void zero_cnt_kernel(int4* __restrict__ cnt4) {
    cnt4[threadIdx.x] = make_int4(0, 0, 0, 0);  // 256 * 16B = 4 KB = NTILES ints
}

// ---------------- phase 1: transform + bin ----------------
__global__ __launch_bounds__(256) void transform_bin_kernel(
    const float* __restrict__ points, const float* __restrict__ w2v,
    const float* __restrict__ p2n, int* __restrict__ cnt,
    float4* __restrict__ entries) {
    int gid = blockIdx.x * 256 + threadIdx.x;
    if (gid >= B * N) return;
    int b = gid >> 13;           // N = 8192
    int n = gid & (N - 1);
    float x = points[(size_t)gid * 3 + 0];
    float y = points[(size_t)gid * 3 + 1];
    float z = points[(size_t)gid * 3 + 2];
    float xn, yn, zn;
    transform_point(w2v, p2n, x, y, z, xn, yn, zn);
    if (!(zn > 0.0f)) return;    // can never be "inside"

    const float rbin = 0.0201f;  // conservative: RADIUS + slack
    int wmin = (int)ceilf(((1.0f - xn) - rbin) * 64.0f - 0.5f);
    int wmax = (int)floorf(((1.0f - xn) + rbin) * 64.0f - 0.5f);
    int hmin = (int)ceilf(((1.0f - yn) - rbin) * 64.0f - 0.5f);
    int hmax = (int)floorf(((1.0f - yn) + rbin) * 64.0f - 0.5f);
    wmin = max(wmin, 0); wmax = min(wmax, W - 1);
    hmin = max(hmin, 0); hmax = min(hmax, H - 1);
    if (wmin > wmax || hmin > hmax) return;

    int txmin = wmin >> 3, txmax = wmax >> 3;
    int tymin = hmin >> 3, tymax = hmax >> 3;
    float4 e; e.x = xn; e.y = yn; e.z = zn; e.w = __int_as_float(n);
    for (int ty = tymin; ty <= tymax; ++ty)
        for (int tx = txmin; tx <= txmax; ++tx) {
            int t = b * TILES_PER_IMG + ty * TILES_X + tx;
            int pos = atomicAdd(&cnt[t], 1);
            if (pos < CAP) entries[(size_t)t * CAP + pos] = e;
        }
}

// ---------------- phase 2: per-tile rasterize ----------------
__global__ __launch_bounds__(64) void raster_kernel(
    const int* __restrict__ cnt, const float4* __restrict__ entries,
    float* __restrict__ out) {
    int t = blockIdx.x;              // 0..NTILES-1
    int count = cnt[t];              // issue load early
    int b = t >> 8;                  // 256 tiles per image
    int ti = t & 255;
    int ty = ti >> 4, tx = ti & 15;
    int lane = threadIdx.x;          // 0..63
    int h = ty * TP + (lane >> 3);
    int w = tx * TP + (lane & 7);
    float px = 1.0f - (2.0f * (float)w + 1.0f) / 128.0f;
    float py = 1.0f - (2.0f * (float)h + 1.0f) / 128.0f;
    const float r2 = (float)(0.02 * 0.02);

    __shared__ float4 sh[64];

    float zk[K]; int ik[K]; float dk[K];
#pragma unroll
    for (int j = 0; j < K; ++j) { zk[j] = BIGF; ik[j] = 0x7fffffff; dk[j] = 0.0f; }

    if (count > CAP) count = CAP;
    const float4* base = entries + (size_t)t * CAP;

    for (int c = 0; c < count; c += 64) {
        if (c + lane < count) sh[lane] = base[c + lane];
        __syncthreads();
        int m = min(64, count - c);
        for (int e = 0; e < m; ++e)
            process_candidate(sh[e], px, py, r2, zk, ik, dk);
        __syncthreads();
    }
    write_out(out, b, h, w, zk, ik, dk);
}

// ---------------- fallback: brute force (no workspace needed) ----------------
__global__ __launch_bounds__(256) void brute_kernel(
    const float* __restrict__ points, const float* __restrict__ w2v,
    const float* __restrict__ p2n, float* __restrict__ out) {
    int gid = blockIdx.x * 256 + threadIdx.x;   // 0..B*H*W-1
    int b = gid >> 14;                           // H*W = 16384
    int rem = gid & 16383;
    int h = rem >> 7, w = rem & 127;
    float px = 1.0f - (2.0f * (float)w + 1.0f) / 128.0f;
    float py = 1.0f - (2.0f * (float)h + 1.0f) / 128.0f;
    const float r2 = (float)(0.02 * 0.02);

    __shared__ float4 sh[256];

    float zk[K]; int ik[K]; float dk[K];
#pragma unroll
    for (int j = 0; j < K; ++j) { zk[j] = BIGF; ik[j] = 0x7fffffff; dk[j] = 0.0f; }

    for (int c = 0; c < N; c += 256) {
        __syncthreads();
        int n = c + threadIdx.x;
        float x = points[((size_t)b * N + n) * 3 + 0];
        float y = points[((size_t)b * N + n) * 3 + 1];
        float z = points[((size_t)b * N + n) * 3 + 2];
        float xn, yn, zn;
        transform_point(w2v, p2n, x, y, z, xn, yn, zn);
        sh[threadIdx.x] = make_float4(xn, yn, zn, __int_as_float(n));
        __syncthreads();
        for (int e = 0; e < 256; ++e)
            process_candidate(sh[e], px, py, r2, zk, ik, dk);
    }
    write_out(out, b, h, w, zk, ik, dk);
}

extern "C" void kernel_launch(void* const* d_in, const int* in_sizes, int n_in,
                              void* d_out, int out_size, void* d_ws, size_t ws_size,
                              hipStream_t stream) {
    const float* points = (const float*)d_in[0];
    const float* w2v    = (const float*)d_in[1];
    const float* p2n    = (const float*)d_in[2];
    float* out = (float*)d_out;

    const size_t ent_off = 4096;
    const size_t need    = ent_off + (size_t)NTILES * CAP * sizeof(float4); // ~4.2 MB

    if (ws_size >= need) {
        int* cnt = (int*)d_ws;
        float4* entries = (float4*)((char*)d_ws + ent_off);
        zero_cnt_kernel<<<1, 256, 0, stream>>>((int4*)cnt);
        transform_bin_kernel<<<(B * N + 255) / 256, 256, 0, stream>>>(points, w2v, p2n, cnt, entries);
        raster_kernel<<<NTILES, 64, 0, stream>>>(cnt, entries, out);
    } else {
        brute_kernel<<<(B * H * W) / 256, 256, 0, stream>>>(points, w2v, p2n, out);
    }
}